// Round 15
// baseline (40.669 us; speedup 1.0000x reference)
//
#include <hip/hip_runtime.h>
#include <math.h>

#define BB 4
#define NN 16384
#define CC 128
#define MM 128
#define SS 512
#define OUT_ROW 131                    // 3 coords + 128 features
#define NSEG 256                       // 16384 / 64 segments per box
#define ELEMS_PER_BOX (SS * OUT_ROW)   // 67072
#define QPBOX (ELEMS_PER_BOX / 4)      // 16768 quads per box

typedef float f32x4 __attribute__((ext_vector_type(4)));

// ---------------- Fused select + gather, one block per box ----------------
// 512 blocks x 1024 threads (16 waves): selection once per box, indices in
// LDS, then whole-box gather. R15 change (single variable vs R14): a
// sched_barrier(0) pins the 4-load batch BEFORE the 4-store batch so the
// scheduler cannot serialize load->store pairs to save registers (R14
// showed VGPR_Count=16 => MLP was crushed to ~1 outstanding gather/thread).
__global__ __launch_bounds__(1024, 8) void roipool_fused(
    const float* __restrict__ points,   // (B, N, 3)
    const float* __restrict__ feats,    // (B, N, C)
    const float* __restrict__ boxes,    // (B, M, 7)
    float* __restrict__ out_feat,       // (B, M, S, 131)
    float* __restrict__ out_flag)       // (B*M) as float 0/1
{
    const int orig = blockIdx.x;
    const int bm   = ((orig & 7) << 6) | (orig >> 3);   // 512 = 8 XCD x 64
    const int b    = bm >> 7;
    const int m    = bm & (MM - 1);
    const int tid  = threadIdx.x;
    const int lane = tid & 63;
    const int wave = tid >> 6;          // 0..15

    __shared__ unsigned long long s_mask[NSEG];
    __shared__ int s_wsum[4];
    __shared__ int s_idx[SS];

    // ---- box params, enlarged: cz -= 0.5, d* += 1.0 ----
    const float* bx = boxes + (size_t)(b * MM + m) * 7;
    const float cx  = bx[0];
    const float cy  = bx[1];
    const float cz  = __fadd_rn(bx[2], -0.5f);
    const float hx  = __fmul_rn(__fadd_rn(bx[3], 1.0f), 0.5f);
    const float hy  = __fmul_rn(__fadd_rn(bx[4], 1.0f), 0.5f);
    const float hz  = __fmul_rn(__fadd_rn(bx[5], 1.0f), 0.5f);
    const float yaw = bx[6];
    const float cosa = (float)cos((double)yaw);
    const float sina = (float)sin((double)yaw);
    const float zc   = __fadd_rn(cz, hz);

    const float* pb = points + (size_t)b * NN * 3;
    const float* fb = feats + (size_t)b * NN * CC;

    // ---- Pass A: wave w ballots segments [w*16, w*16+16) ----
    #pragma unroll 4
    for (int k = 0; k < 16; ++k) {
        const int s = wave * 16 + k;
        const int i = s * 64 + lane;
        const float px = pb[i * 3 + 0];
        const float py = pb[i * 3 + 1];
        const float pz = pb[i * 3 + 2];
        const float sx = __fadd_rn(px, -cx);
        const float sy = __fadd_rn(py, -cy);
        const float lx = __fadd_rn(__fmul_rn(sx, cosa), __fmul_rn(sy, sina));
        const float ly = __fadd_rn(__fmul_rn(-sx, sina), __fmul_rn(sy, cosa));
        const bool in_box = (fabsf(lx) < hx) & (fabsf(ly) < hy) &
                            (fabsf(__fadd_rn(pz, -zc)) <= hz);
        const unsigned long long mask = __ballot(in_box);
        if (lane == 0) s_mask[s] = mask;
    }
    __syncthreads();

    // ---- Pass B: prefix scan over 256 segment counts (threads 0..255) ----
    unsigned long long mymask = 0ull;
    int c = 0;
    if (tid < NSEG) {
        mymask = s_mask[tid];
        c = __popcll(mymask);
    }
    int inc = c;
    #pragma unroll
    for (int d = 1; d < 64; d <<= 1) {
        int v = __shfl_up(inc, d);
        if (lane >= d) inc += v;
    }
    if (tid < NSEG && lane == 63) s_wsum[wave] = inc;
    __syncthreads();

    int woff = 0, total = 0;
    #pragma unroll
    for (int w = 0; w < 4; ++w) {
        const int v = s_wsum[w];
        if (w < wave) woff += v;
        total += v;
    }
    const int cnt = total;

    f32x4* oq = (f32x4*)out_feat + (size_t)bm * QPBOX;

    if (cnt == 0) {
        if (tid == 0) out_flag[bm] = 1.0f;
        const f32x4 z = (f32x4)0.0f;
        #pragma unroll
        for (int it = 0; it < 16; ++it)
            __builtin_nontemporal_store(z, oq + it * 1024 + tid);
        if (tid < QPBOX - 16384)
            __builtin_nontemporal_store(z, oq + 16384 + tid);
        return;
    }
    if (tid == 0) out_flag[bm] = 0.0f;

    // ---- Pass C: stable emit of first SS indices into LDS ----
    if (tid < NSEG) {
        int base = woff + inc - c;          // exclusive prefix
        if (base < SS) {
            unsigned long long mk = mymask;
            while (mk) {
                const int bit = __ffsll(mk) - 1;
                mk &= mk - 1;
                s_idx[base] = tid * 64 + bit;
                if (++base >= SS) break;
            }
        }
    }
    __syncthreads();

    // ---- Pass D: wrap expansion (row % cnt) in LDS ----
    if (cnt < SS) {
        for (int row = cnt + tid; row < SS; row += 1024)
            s_idx[row] = s_idx[row % cnt];
    }
    __syncthreads();

    // ---- Phase 2: gather the whole box (16768 quads) ----
    #pragma unroll
    for (int bt = 0; bt < 4; ++bt) {
        f32x4 vv[4];
        // load batch (4 independent quads in flight)
        #pragma unroll
        for (int j = 0; j < 4; ++j) {
            const int e4 = (bt * 4 + j) * 1024 + tid;
            const int e  = e4 * 4;
            const int rl  = e / 131;
            const int col = e - rl * 131;
            if (col >= 3 && col <= 127) {
                const int pi = s_idx[rl];
                f32x4 v;
                __builtin_memcpy(&v, fb + (size_t)pi * CC + (col - 3), 16);
                vv[j] = v;
            } else {
                f32x4 v;
                #pragma unroll
                for (int jj = 0; jj < 4; ++jj) {
                    const int gg    = col + jj;
                    const int cross = (gg >= OUT_ROW) ? 1 : 0;
                    const int rl2   = rl + cross;
                    const int c2    = gg - cross * OUT_ROW;
                    const int pi2   = s_idx[rl2 < SS ? rl2 : SS - 1];
                    v[jj] = (c2 < 3) ? pb[pi2 * 3 + c2]
                                     : fb[(size_t)pi2 * CC + (c2 - 3)];
                }
                vv[j] = v;
            }
        }
        // pin: loads above may NOT be interleaved into the stores below
        __builtin_amdgcn_sched_barrier(0);
        // store batch
        #pragma unroll
        for (int j = 0; j < 4; ++j)
            __builtin_nontemporal_store(vv[j], oq + (bt * 4 + j) * 1024 + tid);
    }
    // tail: 384 quads
    if (tid < QPBOX - 16384) {
        const int e4 = 16384 + tid;
        const int e  = e4 * 4;
        const int rl  = e / 131;
        const int col = e - rl * 131;
        f32x4 v;
        if (col >= 3 && col <= 127) {
            const int pi = s_idx[rl];
            __builtin_memcpy(&v, fb + (size_t)pi * CC + (col - 3), 16);
        } else {
            #pragma unroll
            for (int jj = 0; jj < 4; ++jj) {
                const int gg    = col + jj;
                const int cross = (gg >= OUT_ROW) ? 1 : 0;
                const int rl2   = rl + cross;
                const int c2    = gg - cross * OUT_ROW;
                const int pi2   = s_idx[rl2 < SS ? rl2 : SS - 1];
                v[jj] = (c2 < 3) ? pb[pi2 * 3 + c2]
                                 : fb[(size_t)pi2 * CC + (c2 - 3)];
            }
        }
        __builtin_nontemporal_store(v, oq + e4);
    }
}

extern "C" void kernel_launch(void* const* d_in, const int* in_sizes, int n_in,
                              void* d_out, int out_size, void* d_ws, size_t ws_size,
                              hipStream_t stream) {
    const float* points = (const float*)d_in[0];
    const float* feats  = (const float*)d_in[1];
    const float* boxes  = (const float*)d_in[2];
    float* out_feat = (float*)d_out;
    float* out_flag = (float*)d_out + (size_t)BB * MM * SS * OUT_ROW;

    roipool_fused<<<BB * MM, 1024, 0, stream>>>(points, feats, boxes,
                                                out_feat, out_flag);
}